// Round 11
// baseline (4101.310 us; speedup 1.0000x reference)
//
#include <hip/hip_runtime.h>
#include <math.h>

typedef _Float16 h2_t __attribute__((ext_vector_type(2)));

#define U_ 256
#define NN 128
#define MM 64
#define OUT_ 8
#define CLIPV 20.0f
#define IN_DIM_ 9
#define PP 268
#define B_ 128
#define T_ 130
#define TSTART 65

// ws element counts / byte offsets
#define NWX2 10240      // 2hf * 16wv * 5p * 64ln   (uint4)
#define NWH2 32768      // 2hf * 32kkq * 512col     (uint4)
#define NWP2 8704       // 2hf * 34cg * 128slot     (uint4)
#define WX2_OFF 0
#define WH2_OFF 163840
#define WP2_OFF 688128
#define BLH_OFF 827392
#define BPP_OFF 831488
#define COMM_OFF 832640
#define COMM_STRIDE 2176          // hA512|hB512|pA544|pB544|flags|pad
#define COMM_SZ (B_*COMM_STRIDE)
#define PREP_N (NWX2 + NWH2 + NWP2 + 256 + 272)

__device__ __forceinline__ float sigf(float x){ return 1.0f/(1.0f+__expf(-x)); }
__device__ __forceinline__ float splus(float x){ return log1pf(__expf(x)); }
__device__ __forceinline__ float clipf(float x){ return fminf(fmaxf(x,-CLIPV),CLIPV); }

#if defined(__has_builtin)
#if __has_builtin(__builtin_amdgcn_fdot2)
#define DOT2(a,b,c) __builtin_amdgcn_fdot2((a),(b),(c),false)
#endif
#endif
#ifndef DOT2
#define DOT2(a,b,c) fmaf((float)(a).x,(float)(b).x, fmaf((float)(a).y,(float)(b).y,(c)))
#endif

// 4 column-accumulators vs one h2
#define DOT2X4(uu, hv) { \
    a0 = DOT2(hv, __builtin_bit_cast(h2_t,(uu).x), a0); \
    a1 = DOT2(hv, __builtin_bit_cast(h2_t,(uu).y), a1); \
    a2 = DOT2(hv, __builtin_bit_cast(h2_t,(uu).z), a2); \
    a3 = DOT2(hv, __builtin_bit_cast(h2_t,(uu).w), a3); }
#define DOT2P(uu, hv) { \
    pa0 = DOT2(hv, __builtin_bit_cast(h2_t,(uu).x), pa0); \
    pa1 = DOT2(hv, __builtin_bit_cast(h2_t,(uu).y), pa1); \
    pa2 = DOT2(hv, __builtin_bit_cast(h2_t,(uu).z), pa2); \
    pa3 = DOT2(hv, __builtin_bit_cast(h2_t,(uu).w), pa3); }
// elementwise 8-MAC: uint4 weights (4 kk-pairs) vs uint4 of h pairs
#define DOT2E(uu, hh) { \
    accG = DOT2(__builtin_bit_cast(h2_t,(hh).x), __builtin_bit_cast(h2_t,(uu).x), accG); \
    accG = DOT2(__builtin_bit_cast(h2_t,(hh).y), __builtin_bit_cast(h2_t,(uu).y), accG); \
    accG = DOT2(__builtin_bit_cast(h2_t,(hh).z), __builtin_bit_cast(h2_t,(uu).z), accG); \
    accG = DOT2(__builtin_bit_cast(h2_t,(hh).w), __builtin_bit_cast(h2_t,(uu).w), accG); }

__device__ __forceinline__ unsigned packh2(float a, float b){
    h2_t v; v.x = (_Float16)a; v.y = (_Float16)b;
    return __builtin_bit_cast(unsigned, v);
}

__global__ void prep_kernel(const float* __restrict__ W_x, const float* __restrict__ W_h,
                            const float* __restrict__ W_p, const float* __restrict__ b_lstm,
                            const float* __restrict__ b_p,
                            uint4* __restrict__ wx2, uint4* __restrict__ wh2,
                            uint4* __restrict__ wp2,
                            float4* __restrict__ blh, float* __restrict__ bpp)
{
    for (int idx = blockIdx.x*blockDim.x + threadIdx.x; idx < PREP_N; idx += gridDim.x*blockDim.x){
        if (idx < NWX2){
            // conflict-free pinned layout: [hf][wv][p][ln]
            int hf = idx/5120, rem = idx - hf*5120;
            int wv = rem/320, r2 = rem - wv*320, p = r2>>6, ln = r2&63;
            int g4 = wv*8 + (ln>>3), q = ln&7, kk = q*5+p;
            int k0 = 2*kk, k1 = k0+1;
            unsigned c[4];
            #pragma unroll
            for (int g=0; g<4; ++g){
                int col = g*256 + hf*128 + g4;
                float f0 = (k0<64) ? W_x[(9+k0)*1024+col] : (k0<73 ? W_x[(k0-64)*1024+col] : 0.f);
                float f1 = (k1<64) ? W_x[(9+k1)*1024+col] : (k1<73 ? W_x[(k1-64)*1024+col] : 0.f);
                c[g] = packh2(f0,f1);
            }
            wx2[idx] = make_uint4(c[0],c[1],c[2],c[3]);
        } else if (idx < NWX2 + NWH2){
            // streaming layout: [hf][kkq][col] uint4 = 4 consecutive kk-pairs of one col
            int e = idx - NWX2;
            int hf = e>>14, rem = e&16383, kkq = rem>>9, cc = rem&511;
            int g4 = cc>>2, g = cc&3, col = g*256 + hf*128 + g4;
            unsigned c[4];
            #pragma unroll
            for (int j=0; j<4; ++j){
                int kk = 4*kkq + j;
                c[j] = packh2(W_h[(2*kk)*1024+col], W_h[(2*kk+1)*1024+col]);
            }
            wh2[e] = make_uint4(c[0],c[1],c[2],c[3]);
        } else if (idx < NWX2 + NWH2 + NWP2){
            // params: [hf][cg][slot s=p*8+q], kk = (p<8)? q*8+p : 64+q*8+(p-8)
            int e = idx - NWX2 - NWH2;
            int hf = e/4352, rem = e - hf*4352, cg = rem>>7, s = rem&127;
            int p = s>>3, q = s&7;
            int kk = (p<8) ? (q*8+p) : (64 + q*8 + (p-8));
            unsigned c[4];
            #pragma unroll
            for (int g=0; g<4; ++g){
                int cl = cg*4+g, rc = hf*134+cl;
                c[g] = (cl<134) ? packh2(W_p[(2*kk)*PP+rc], W_p[(2*kk+1)*PP+rc]) : 0u;
            }
            wp2[e] = make_uint4(c[0],c[1],c[2],c[3]);
        } else if (idx < NWX2 + NWH2 + NWP2 + 256){
            int u = idx - NWX2 - NWH2 - NWP2;
            blh[u] = make_float4(b_lstm[u], b_lstm[256+u], b_lstm[512+u], b_lstm[768+u]);
        } else {
            int j = idx - NWX2 - NWH2 - NWP2 - 256;
            bpp[j] = (j < PP) ? b_p[j] : 0.f;
        }
    }
}

__device__ __forceinline__ float decodeP(int rc, float p){
    if (rc < 64 || (rc >= 70 && rc < 134) || rc >= 204) return tanhf(p);
    if (rc >= 140 && rc < 204) return sigf(p);
    return p;
}

__global__ __launch_bounds__(1024,1) void ntm_kernel(
    const float* __restrict__ inputs,
    const float* __restrict__ W_o, const float* __restrict__ b_o,
    const float* __restrict__ r0, const float* __restrict__ w0,
    const uint4* __restrict__ wx2, const uint4* __restrict__ whg2,
    const uint4* __restrict__ wpg,
    const float4* __restrict__ blh, const float* __restrict__ bpp,
    char* comm, float* __restrict__ out)
{
    const int bid = blockIdx.x, hf = bid>>7, b = bid&127;
    const int t = threadIdx.x, wv = t>>6, ln = t&63;
    const int g4 = t>>3, q = t&7;
    const int tt = t&511, kh = t>>9;

    char* cb = comm + b*COMM_STRIDE;
    volatile float* hOwn = (volatile float*)(cb + hf*512);
    volatile float* hOth = (volatile float*)(cb + (hf^1)*512);
    volatile float* pOwn = (volatile float*)(cb + 1024 + hf*544);
    volatile float* pOth = (volatile float*)(cb + 1024 + (hf^1)*544);
    volatile int*   flg  = (volatile int*)(cb + 2112);   // [f1A,f1B,f2A,f2B]

    __shared__ uint4 wxL[5120];          // 80KB pinned W_x half (conflict-free layout)
    __shared__ float Mem[NN][MM+1];
    __shared__ float gpartH[2][512];
    __shared__ float4 blhL[128];
    __shared__ float hbuf[U_];
    __shared__ float cbuf[128];
    __shared__ h2_t  hb2[128] __attribute__((aligned(16)));
    __shared__ h2_t  xr2[40] __attribute__((aligned(16)));
    __shared__ float prmS[12];
    __shared__ float scal[12];
    __shared__ float kv[2][MM], ebuf[MM], abuf[MM];
    __shared__ float innr[2][NN], Mn[NN], wgs[2][NN], wtab[2][NN];
    __shared__ float rpart[8][MM];
    __shared__ float jpart[OUT_];

    // ---- init ----
    for (int i=t; i<5120; i+=1024) wxL[i] = wx2[hf*5120 + i];
    for (int i=t; i<NN*MM; i+=1024) Mem[i>>6][i&63] = 1e-6f;
    if (t < 512){ gpartH[0][t] = 0.f; gpartH[1][t] = 0.f; }
    if (t < 128){
        blhL[t] = blh[hf*128+t];
        cbuf[t] = 0.f;
        Mn[t] = 8e-6f;
        h2_t z; z.x=(_Float16)0.f; z.y=(_Float16)0.f; hb2[t] = z;
    }
    if (t < U_) hbuf[t] = 0.f;
    if (t >= 128 && t < 256){  // wtab = softmax(w0)
        int h = (t-128)>>6, l = t&63;
        float v0 = w0[h*NN + l], v1 = w0[h*NN + l + 64];
        float mx = fmaxf(v0,v1);
        for (int off=32; off>=1; off>>=1) mx = fmaxf(mx, __shfl_xor(mx, off));
        float e0 = __expf(v0-mx), e1 = __expf(v1-mx);
        float s = e0+e1;
        for (int off=32; off>=1; off>>=1) s += __shfl_xor(s, off);
        wtab[h][l] = e0/s; wtab[h][l+64] = e1/s;
    }
    if (t >= 256 && t < 296){
        int p = t-256;
        h2_t v;
        if (p < 32){ v.x = (_Float16)tanhf(r0[2*p]); v.y = (_Float16)tanhf(r0[2*p+1]); }
        else if (p < 37){
            int e0 = 2*(p-32), e1 = e0+1;
            float f0 = (e0<IN_DIM_) ? inputs[b*T_*IN_DIM_ + e0] : 0.f;
            float f1 = (e1<IN_DIM_) ? inputs[b*T_*IN_DIM_ + e1] : 0.f;
            v.x = (_Float16)f0; v.y = (_Float16)f1;
        } else { v.x=(_Float16)0.f; v.y=(_Float16)0.f; }
        xr2[p] = v;
    }
    __syncthreads();

    for (int step=0; step<T_; ++step){
        float accG = 0.f;                  // gpart accumulator (chunks in tail)
        float pa0=0.f, pa1=0.f, pa2=0.f, pa3=0.f;

        // ---- B: gates from pinned wx (conflict-free) + gpart + bias, fused LSTM ----
        {
            const uint4* wb = wxL + wv*320;
            float a0=0.f,a1=0.f,a2=0.f,a3=0.f;
            #pragma unroll
            for (int p=0; p<5; ++p){
                uint4 u = wb[p*64 + ln];
                h2_t xv = xr2[q*5+p];
                DOT2X4(u, xv);
            }
            #pragma unroll
            for (int m=1; m<8; m<<=1){
                a0 += __shfl_xor(a0,m); a1 += __shfl_xor(a1,m);
                a2 += __shfl_xor(a2,m); a3 += __shfl_xor(a3,m);
            }
            if (q==0){
                float4 bb = blhL[g4];
                const float4 gp0 = ((const float4*)&gpartH[0][0])[g4];
                const float4 gp1 = ((const float4*)&gpartH[1][0])[g4];
                float gi=a0+bb.x+gp0.x+gp1.x, gf=a1+bb.y+gp0.y+gp1.y;
                float gg=a2+bb.z+gp0.z+gp1.z, go=a3+bb.w+gp0.w+gp1.w;
                float c = sigf(gf)*cbuf[g4] + sigf(gi)*tanhf(gg);
                cbuf[g4] = c;
                hbuf[hf*128+g4] = sigf(go)*tanhf(c);
            }
        }
        __syncthreads();

        // ---- X1: export own h (coalesced), build own fp16 pairs ----
        if (t < 128) hOwn[t] = hbuf[hf*128 + t];
        else if (t < 192){
            int j = t-128;
            h2_t v; v.x=(_Float16)hbuf[hf*128+2*j]; v.y=(_Float16)hbuf[hf*128+2*j+1];
            hb2[hf*64+j] = v;
        }
        __syncthreads();                       // drain h stores
        if (t==0) flg[hf] = step+1;

        // ---- 2a: params own K-half + Mn + x-prefetch (overlaps partner h transit) ----
        if (t < 272){
            const int cg = t>>3, qq = t&7;
            const uint4* wrow = wpg + (hf*34+cg)*128;
            #pragma unroll 4
            for (int pp=0; pp<8; ++pp){
                int p = hf*8 + pp;
                int kk = (p<8) ? (qq*8+p) : (64 + qq*8 + (p-8));
                uint4 u = wrow[p*8+qq];
                h2_t hv = hb2[kk];
                DOT2P(u, hv);
            }
        } else if (t < 528){
            const int idx = t-272, n = idx>>1, m0 = (idx&1)*32;
            float s = 0.f;
            #pragma unroll 8
            for (int m=m0; m<m0+32; ++m){ float v=Mem[n][m]; s=fmaf(v,v,s); }
            s += __shfl_xor(s,1);
            if (!(idx&1)) Mn[n] = sqrtf(s);
        } else if (t < 533){
            if (step+1 < T_){
                const int p = t-528;
                const int e0 = 2*p, e1 = e0+1;
                const float* xin = inputs + (b*T_ + step+1)*IN_DIM_;
                h2_t v;
                v.x = (_Float16)((e0<IN_DIM_) ? xin[e0] : 0.f);
                v.y = (_Float16)((e1<IN_DIM_) ? xin[e1] : 0.f);
                xr2[32+p] = v;
            }
        }
        if (t==0){ while (flg[hf^1] < step+1) __builtin_amdgcn_s_sleep(8); }
        __syncthreads();

        // ---- X2: import partner h ----
        if (t < 128){
            float hv = hOth[t];
            hbuf[(hf^1)*128 + t] = hv;
            float hv2 = __shfl_down(hv, 1);
            if (!(t&1)){ h2_t vv; vv.x=(_Float16)hv; vv.y=(_Float16)hv2; hb2[(hf^1)*64 + (t>>1)] = vv; }
        }
        __syncthreads();

        // ---- 2b: params partner K-half + decode + export; jpart (full h) ----
        if (t < 272){
            const int cg = t>>3, qq = t&7;
            const uint4* wrow = wpg + (hf*34+cg)*128;
            #pragma unroll 4
            for (int pp=0; pp<8; ++pp){
                int p = (hf^1)*8 + pp;
                int kk = (p<8) ? (qq*8+p) : (64 + qq*8 + (p-8));
                uint4 u = wrow[p*8+qq];
                h2_t hv = hb2[kk];
                DOT2P(u, hv);
            }
            #pragma unroll
            for (int m=1; m<8; m<<=1){
                pa0 += __shfl_xor(pa0,m); pa1 += __shfl_xor(pa1,m);
                pa2 += __shfl_xor(pa2,m); pa3 += __shfl_xor(pa3,m);
            }
            if (qq==0){
                #pragma unroll
                for (int j=0; j<4; ++j){
                    float aj = (j==0)?pa0:((j==1)?pa1:((j==2)?pa2:pa3));
                    int cl = cg*4+j;
                    if (cl < 134){
                        int rc = hf*134+cl;
                        float pv = clipf(aj + bpp[rc]);
                        float dv = decodeP(rc, pv);
                        pOwn[cl] = dv;
                        if (rc < 64) kv[0][rc] = dv;
                        else if (rc < 70) prmS[rc-64] = dv;
                        else if (rc < 134) kv[1][rc-70] = dv;
                        else if (rc < 140) prmS[6+rc-134] = dv;
                        else if (rc < 204) ebuf[rc-140] = dv;
                        else abuf[rc-204] = dv;
                    }
                }
            }
        } else if (t >= 528 && t < 656){
            const int o = (t-528)>>4, l16 = (t-528)&15;
            float s = 0.f;
            #pragma unroll
            for (int j=0; j<16; ++j){
                const int i = l16 + (j<<4);
                s = fmaf(hbuf[i], W_o[i*OUT_ + o], s);
            }
            s += __shfl_xor(s,1); s += __shfl_xor(s,2);
            s += __shfl_xor(s,4); s += __shfl_xor(s,8);
            if (l16==0) jpart[o] = s;
        }
        __syncthreads();                       // drain pOwn stores
        if (t==0){
            flg[2+hf] = step+1;
            while (flg[2+(hf^1)] < step+1) __builtin_amdgcn_s_sleep(8);
        }
        __syncthreads();

        // ---- route partner's decoded params ----
        if (t < 134){
            float dv = pOth[t];
            int rc = (hf^1)*134 + t;
            if (rc < 64) kv[0][rc] = dv;
            else if (rc < 70) prmS[rc-64] = dv;
            else if (rc < 134) kv[1][rc-70] = dv;
            else if (rc < 140) prmS[6+rc-134] = dv;
            else if (rc < 204) ebuf[rc-140] = dv;
            else abuf[rc-204] = dv;
        }
        __syncthreads();

        const uint4* hb2q = (const uint4*)hb2;

        // ---- F ∥ gpart chunk0: innr + scal decode ----
        #pragma unroll 4
        for (int j=0; j<4; ++j){
            int kkq = kh*16 + j;
            uint4 u = whg2[hf*16384 + kkq*512 + tt];
            uint4 hq = hb2q[kkq];
            DOT2E(u, hq);
        }
        if (t < 256){
            const int h = t>>7, n = t&127;
            float s = 0.f;
            #pragma unroll 8
            for (int m=0; m<MM; ++m) s = fmaf(kv[h][m], Mem[n][m], s);
            innr[h][n] = s;
        } else if (t >= 384 && t < 386){
            const int h = t-384;
            const float* ps = prmS + 6*h;
            scal[h]   = splus(ps[0]);
            scal[2+h] = sigf(ps[1]);
            float p0=ps[2], p1=ps[3], p2=ps[4];
            float mx = fmaxf(p0, fmaxf(p1, p2));
            float e0=__expf(p0-mx), e1=__expf(p1-mx), e2=__expf(p2-mx);
            float s = e0+e1+e2;
            scal[6+3*h]=e0/s; scal[7+3*h]=e1/s; scal[8+3*h]=e2/s;
            scal[4+h] = 1.f + splus(ps[5]);
        }
        __syncthreads();

        // ---- G ∥ chunk1 ----
        #pragma unroll 4
        for (int j=0; j<4; ++j){
            int kkq = kh*16 + 4 + j;
            uint4 u = whg2[hf*16384 + kkq*512 + tt];
            uint4 hq = hb2q[kkq];
            DOT2E(u, hq);
        }
        if (t < 128){
            const int h = t>>6, l = ln;
            float kvl = kv[h][l];
            float kn2 = kvl*kvl;
            for (int off=32; off>=1; off>>=1) kn2 += __shfl_xor(kn2, off);
            float kn = sqrtf(kn2);
            float beta = scal[h], g = scal[2+h];
            float bk0 = beta * innr[h][l]   /(kn*Mn[l]   +1e-8f);
            float bk1 = beta * innr[h][l+64]/(kn*Mn[l+64]+1e-8f);
            float mx = fmaxf(bk0,bk1);
            for (int off=32; off>=1; off>>=1) mx = fmaxf(mx, __shfl_xor(mx, off));
            float e0=__expf(bk0-mx), e1=__expf(bk1-mx);
            float s=e0+e1;
            for (int off=32; off>=1; off>>=1) s += __shfl_xor(s, off);
            float wc0=e0/s, wc1=e1/s;
            wgs[h][l]    = g*wc0 + (1.f-g)*wtab[h][l];
            wgs[h][l+64] = g*wc1 + (1.f-g)*wtab[h][l+64];
            float gamma = scal[4+h];
            float s0=scal[6+3*h], s1=scal[7+3*h], s2=scal[8+3*h];
            const int n0=l, n1=l+64;
            float wt0 = s0*wgs[h][(n0+1)&127] + s1*wgs[h][n0] + s2*wgs[h][(n0+127)&127];
            float wt1 = s0*wgs[h][(n1+1)&127] + s1*wgs[h][n1] + s2*wgs[h][(n1+127)&127];
            float wp0 = __powf(wt0, gamma), wp1 = __powf(wt1, gamma);
            float ss = wp0+wp1;
            for (int off=32; off>=1; off>>=1) ss += __shfl_xor(ss, off);
            float inv = 1.0f/(ss+1e-8f);
            wtab[h][n0] = wp0*inv; wtab[h][n1] = wp1*inv;
        }
        __syncthreads();

        // ---- H ∥ chunk2: memory write + read-head partials ----
        #pragma unroll 4
        for (int j=0; j<4; ++j){
            int kkq = kh*16 + 8 + j;
            uint4 u = whg2[hf*16384 + kkq*512 + tt];
            uint4 hq = hb2q[kkq];
            DOT2E(u, hq);
        }
        if (wv < 8){
            const float el = ebuf[ln], al = abuf[ln];
            float racc = 0.f;
            #pragma unroll
            for (int k=0; k<16; ++k){
                const int n = wv*16+k;
                float ww = wtab[1][n];
                float wr = wtab[0][n];
                float v = Mem[n][ln]*(1.0f - ww*el) + ww*al;
                Mem[n][ln] = v;
                racc = fmaf(wr, v, racc);
            }
            rpart[wv][ln] = racc;
        }
        __syncthreads();

        // ---- J ∥ chunk3: r finalize + output ; gpart store ----
        #pragma unroll 4
        for (int j=0; j<4; ++j){
            int kkq = kh*16 + 12 + j;
            uint4 u = whg2[hf*16384 + kkq*512 + tt];
            uint4 hq = hb2q[kkq];
            DOT2E(u, hq);
        }
        gpartH[kh][tt] = accG;
        if (wv < 8){
            float rm = 0.f;
            #pragma unroll
            for (int k=0; k<8; ++k) rm += rpart[k][ln];
            if (wv==0){
                float o2 = __shfl_down(rm, 1);
                if (!(ln&1)){ h2_t v; v.x=(_Float16)rm; v.y=(_Float16)o2; xr2[ln>>1] = v; }
            }
            float s = rm * W_o[(U_+ln)*OUT_ + wv];
            for (int off=32; off>=1; off>>=1) s += __shfl_xor(s, off);
            if (ln==0 && hf==0 && step>=TSTART){
                float logit = clipf(s + jpart[wv] + b_o[wv]);
                out[((b*(T_-TSTART)) + (step-TSTART))*OUT_ + wv] = sigf(logit);
            }
        }
        __syncthreads();
    }
}

extern "C" void kernel_launch(void* const* d_in, const int* in_sizes, int n_in,
                              void* d_out, int out_size, void* d_ws, size_t ws_size,
                              hipStream_t stream) {
    const float* inputs = (const float*)d_in[0];
    const float* W_x    = (const float*)d_in[1];
    const float* W_h    = (const float*)d_in[2];
    const float* b_lstm = (const float*)d_in[3];
    const float* W_p    = (const float*)d_in[4];
    const float* b_p    = (const float*)d_in[5];
    const float* W_o    = (const float*)d_in[6];
    const float* b_o    = (const float*)d_in[7];
    const float* r0     = (const float*)d_in[8];
    const float* w0     = (const float*)d_in[9];
    float* out = (float*)d_out;

    char* ws = (char*)d_ws;
    uint4*  wx2 = (uint4*)(ws + WX2_OFF);
    uint4*  wh2 = (uint4*)(ws + WH2_OFF);
    uint4*  wp2 = (uint4*)(ws + WP2_OFF);
    float4* blh = (float4*)(ws + BLH_OFF);
    float*  bpp = (float*)(ws + BPP_OFF);
    char*   comm = ws + COMM_OFF;

    hipMemsetAsync(comm, 0, COMM_SZ, stream);
    prep_kernel<<<512, 256, 0, stream>>>(W_x, W_h, W_p, b_lstm, b_p, wx2, wh2, wp2, blh, bpp);
    ntm_kernel<<<2*B_, 1024, 0, stream>>>(inputs, W_o, b_o, r0, w0,
                                          wx2, wh2, wp2, blh, bpp, comm, out);
}

// Round 12
// 2127.274 us; speedup vs baseline: 1.9280x; 1.9280x over previous
//
#include <hip/hip_runtime.h>
#include <math.h>

typedef _Float16 h2_t __attribute__((ext_vector_type(2)));

#define U_ 256
#define NN 128
#define MM 64
#define OUT_ 8
#define CLIPV 20.0f
#define IN_DIM_ 9
#define PP 268
#define B_ 128
#define T_ 130
#define TSTART 65

// ws element counts / byte offsets
#define NWX2 10240      // 2hf * 16wv * 5p * 64ln        (uint4, conflict-free pinned)
#define NWHG 32768      // 2hf * 128g4 * 128slot(p*8+q)  (uint4, kk=q*16+p)
#define NWPG 8704       // 2hf * 34cg * 128slot(p*8+q)   (uint4, kk=q*16+p)
#define WX2_OFF 0
#define WHG_OFF 163840
#define WPG_OFF 688128
#define BLH_OFF 827392
#define BPP_OFF 831488
#define COMM_OFF 832640
#define COMM_STRIDE 2176          // hA512|hB512|pA544|pB544|flags|pad
#define COMM_SZ (B_*COMM_STRIDE)
#define PREP_N (NWX2 + NWHG + NWPG + 256 + 272)

__device__ __forceinline__ float sigf(float x){ return 1.0f/(1.0f+__expf(-x)); }
__device__ __forceinline__ float splus(float x){ return log1pf(__expf(x)); }
__device__ __forceinline__ float clipf(float x){ return fminf(fmaxf(x,-CLIPV),CLIPV); }

#if defined(__has_builtin)
#if __has_builtin(__builtin_amdgcn_fdot2)
#define DOT2(a,b,c) __builtin_amdgcn_fdot2((a),(b),(c),false)
#endif
#endif
#ifndef DOT2
#define DOT2(a,b,c) fmaf((float)(a).x,(float)(b).x, fmaf((float)(a).y,(float)(b).y,(c)))
#endif

#define DOT2X4(uu, hv) { \
    a0 = DOT2(hv, __builtin_bit_cast(h2_t,(uu).x), a0); \
    a1 = DOT2(hv, __builtin_bit_cast(h2_t,(uu).y), a1); \
    a2 = DOT2(hv, __builtin_bit_cast(h2_t,(uu).z), a2); \
    a3 = DOT2(hv, __builtin_bit_cast(h2_t,(uu).w), a3); }
#define DOT2P(uu, hv) { \
    pa0 = DOT2(hv, __builtin_bit_cast(h2_t,(uu).x), pa0); \
    pa1 = DOT2(hv, __builtin_bit_cast(h2_t,(uu).y), pa1); \
    pa2 = DOT2(hv, __builtin_bit_cast(h2_t,(uu).z), pa2); \
    pa3 = DOT2(hv, __builtin_bit_cast(h2_t,(uu).w), pa3); }
#define H2C(hu) __builtin_bit_cast(h2_t,(hu))

__device__ __forceinline__ unsigned packh2(float a, float b){
    h2_t v; v.x = (_Float16)a; v.y = (_Float16)b;
    return __builtin_bit_cast(unsigned, v);
}

__global__ void prep_kernel(const float* __restrict__ W_x, const float* __restrict__ W_h,
                            const float* __restrict__ W_p, const float* __restrict__ b_lstm,
                            const float* __restrict__ b_p,
                            uint4* __restrict__ wx2, uint4* __restrict__ wh2,
                            uint4* __restrict__ wp2,
                            float4* __restrict__ blh, float* __restrict__ bpp)
{
    for (int idx = blockIdx.x*blockDim.x + threadIdx.x; idx < PREP_N; idx += gridDim.x*blockDim.x){
        if (idx < NWX2){
            // conflict-free pinned layout: [hf][wv][p][ln]
            int hf = idx/5120, rem = idx - hf*5120;
            int wv = rem/320, r2 = rem - wv*320, p = r2>>6, ln = r2&63;
            int g4 = wv*8 + (ln>>3), q = ln&7, kk = q*5+p;
            int k0 = 2*kk, k1 = k0+1;
            unsigned c[4];
            #pragma unroll
            for (int g=0; g<4; ++g){
                int col = g*256 + hf*128 + g4;
                float f0 = (k0<64) ? W_x[(9+k0)*1024+col] : (k0<73 ? W_x[(k0-64)*1024+col] : 0.f);
                float f1 = (k1<64) ? W_x[(9+k1)*1024+col] : (k1<73 ? W_x[(k1-64)*1024+col] : 0.f);
                c[g] = packh2(f0,f1);
            }
            wx2[idx] = make_uint4(c[0],c[1],c[2],c[3]);
        } else if (idx < NWX2 + NWHG){
            int e = idx - NWX2;
            int hf = e>>14, rem = e&16383, g4 = rem>>7, s = rem&127;
            int p = s>>3, q = s&7, kk = q*16+p;
            unsigned c[4];
            #pragma unroll
            for (int g=0; g<4; ++g){
                int col = g*256 + hf*128 + g4;
                c[g] = packh2(W_h[(2*kk)*1024+col], W_h[(2*kk+1)*1024+col]);
            }
            wh2[e] = make_uint4(c[0],c[1],c[2],c[3]);
        } else if (idx < NWX2 + NWHG + NWPG){
            int e = idx - NWX2 - NWHG;
            int hf = e/4352, rem = e - hf*4352, cg = rem>>7, s = rem&127;
            int p = s>>3, q = s&7, kk = q*16+p;
            unsigned c[4];
            #pragma unroll
            for (int g=0; g<4; ++g){
                int cl = cg*4+g, rc = hf*134+cl;
                c[g] = (cl<134) ? packh2(W_p[(2*kk)*PP+rc], W_p[(2*kk+1)*PP+rc]) : 0u;
            }
            wp2[e] = make_uint4(c[0],c[1],c[2],c[3]);
        } else if (idx < NWX2 + NWHG + NWPG + 256){
            int u = idx - NWX2 - NWHG - NWPG;
            blh[u] = make_float4(b_lstm[u], b_lstm[256+u], b_lstm[512+u], b_lstm[768+u]);
        } else {
            int j = idx - NWX2 - NWHG - NWPG - 256;
            bpp[j] = (j < PP) ? b_p[j] : 0.f;
        }
    }
}

__device__ __forceinline__ float decodeP(int rc, float p){
    if (rc < 64 || (rc >= 70 && rc < 134) || rc >= 204) return tanhf(p);
    if (rc >= 140 && rc < 204) return sigf(p);
    return p;
}

__global__ __launch_bounds__(1024,1) void ntm_kernel(
    const float* __restrict__ inputs,
    const float* __restrict__ W_o, const float* __restrict__ b_o,
    const float* __restrict__ r0, const float* __restrict__ w0,
    const uint4* __restrict__ wx2, const uint4* __restrict__ whg,
    const uint4* __restrict__ wpg,
    const float4* __restrict__ blh, const float* __restrict__ bpp,
    char* comm, float* __restrict__ out)
{
    const int bid = blockIdx.x, hf = bid>>7, b = bid&127;
    const int t = threadIdx.x, wv = t>>6, ln = t&63;
    const int g4 = t>>3, q = t&7;

    char* cb = comm + b*COMM_STRIDE;
    volatile float* hOwn = (volatile float*)(cb + hf*512);
    volatile float* hOth = (volatile float*)(cb + (hf^1)*512);
    volatile float* pOwn = (volatile float*)(cb + 1024 + hf*544);
    volatile float* pOth = (volatile float*)(cb + 1024 + (hf^1)*544);
    volatile int*   flg  = (volatile int*)(cb + 2112);   // [f1A,f1B,f2A,f2B]

    __shared__ uint4 wxL[5120];          // 80KB pinned W_x half (conflict-free)
    __shared__ float Mem[NN][MM+1];
    __shared__ float4 gpart4[128];
    __shared__ float4 blhL[128];
    __shared__ float hbuf[U_];
    __shared__ float cbuf[128];
    __shared__ h2_t  hb2[128] __attribute__((aligned(16)));
    __shared__ h2_t  xr2[40] __attribute__((aligned(16)));
    __shared__ float prmS[12];
    __shared__ float scal[12];
    __shared__ float kv[2][MM], ebuf[MM], abuf[MM];
    __shared__ float innr[2][NN], Mn[NN], wgs[2][NN], wtab[2][NN];
    __shared__ float rpart[16][MM];
    __shared__ float jpart[OUT_];

    // ---- init ----
    for (int i=t; i<5120; i+=1024) wxL[i] = wx2[hf*5120 + i];
    for (int i=t; i<NN*MM; i+=1024) Mem[i>>6][i&63] = 1e-6f;
    if (t < 128){
        gpart4[t] = make_float4(0.f,0.f,0.f,0.f);
        blhL[t] = blh[hf*128+t];
        cbuf[t] = 0.f;
        Mn[t] = 8e-6f;
        h2_t z; z.x=(_Float16)0.f; z.y=(_Float16)0.f; hb2[t] = z;
    }
    if (t < U_) hbuf[t] = 0.f;
    if (t >= 128 && t < 256){  // wtab = softmax(w0)
        int h = (t-128)>>6, l = t&63;
        float v0 = w0[h*NN + l], v1 = w0[h*NN + l + 64];
        float mx = fmaxf(v0,v1);
        for (int off=32; off>=1; off>>=1) mx = fmaxf(mx, __shfl_xor(mx, off));
        float e0 = __expf(v0-mx), e1 = __expf(v1-mx);
        float s = e0+e1;
        for (int off=32; off>=1; off>>=1) s += __shfl_xor(s, off);
        wtab[h][l] = e0/s; wtab[h][l+64] = e1/s;
    }
    if (t >= 256 && t < 296){
        int p = t-256;
        h2_t v;
        if (p < 32){ v.x = (_Float16)tanhf(r0[2*p]); v.y = (_Float16)tanhf(r0[2*p+1]); }
        else if (p < 37){
            int e0 = 2*(p-32), e1 = e0+1;
            float f0 = (e0<IN_DIM_) ? inputs[b*T_*IN_DIM_ + e0] : 0.f;
            float f1 = (e1<IN_DIM_) ? inputs[b*T_*IN_DIM_ + e1] : 0.f;
            v.x = (_Float16)f0; v.y = (_Float16)f1;
        } else { v.x=(_Float16)0.f; v.y=(_Float16)0.f; }
        xr2[p] = v;
    }
    __syncthreads();

    for (int step=0; step<T_; ++step){
        // ---- B: gates from pinned wx (conflict-free) + gpart + bias, fused LSTM ----
        {
            const uint4* wb = wxL + wv*320;
            float a0=0.f,a1=0.f,a2=0.f,a3=0.f;
            #pragma unroll
            for (int p=0; p<5; ++p){
                uint4 u = wb[p*64 + ln];
                h2_t xv = xr2[q*5+p];
                DOT2X4(u, xv);
            }
            #pragma unroll
            for (int m=1; m<8; m<<=1){
                a0 += __shfl_xor(a0,m); a1 += __shfl_xor(a1,m);
                a2 += __shfl_xor(a2,m); a3 += __shfl_xor(a3,m);
            }
            if (q==0){
                float4 bb = blhL[g4]; float4 gp = gpart4[g4];
                float gi=a0+bb.x+gp.x, gf=a1+bb.y+gp.y, gg=a2+bb.z+gp.z, go=a3+bb.w+gp.w;
                float c = sigf(gf)*cbuf[g4] + sigf(gi)*tanhf(gg);
                cbuf[g4] = c;
                float h = sigf(go)*tanhf(c);
                hbuf[hf*128+g4] = h;
                hOwn[g4] = h;
            }
        }
        __syncthreads();                          // drains volatile h stores
        if (t==0){
            flg[hf] = step+1;
            while (flg[hf^1] < step+1) __builtin_amdgcn_s_sleep(8);
        }
        __syncthreads();
        // pull partner h; build fp16 h pairs
        if (t < 128){
            float hv = hOth[t];
            hbuf[(hf^1)*128 + t] = hv;
            float hv2 = __shfl_down(hv, 1);
            if (!(t&1)){ h2_t vv; vv.x=(_Float16)hv; vv.y=(_Float16)hv2; hb2[(hf^1)*64 + (t>>1)] = vv; }
        } else if (t < 192){
            int jj = t-128;
            h2_t vv; vv.x=(_Float16)hbuf[hf*128+2*jj]; vv.y=(_Float16)hbuf[hf*128+2*jj+1];
            hb2[hf*64+jj] = vv;
        }
        __syncthreads();

        const uint4* hb2q = (const uint4*)hb2;

        // ---- FUSED: gpart (all threads, 8-deep batched) ; wp+decode ; Mn ; jpart ; x-pre ----
        {
            const uint4* wrow = whg + hf*16384 + g4*128;
            uint4 hA = hb2q[q*4+0], hB = hb2q[q*4+1], hC = hb2q[q*4+2], hD = hb2q[q*4+3];
            float a0=0.f,a1=0.f,a2=0.f,a3=0.f;
            {
                uint4 u0=wrow[0*8+q], u1=wrow[1*8+q], u2=wrow[2*8+q], u3=wrow[3*8+q];
                uint4 u4=wrow[4*8+q], u5=wrow[5*8+q], u6=wrow[6*8+q], u7=wrow[7*8+q];
                DOT2X4(u0, H2C(hA.x)); DOT2X4(u1, H2C(hA.y));
                DOT2X4(u2, H2C(hA.z)); DOT2X4(u3, H2C(hA.w));
                DOT2X4(u4, H2C(hB.x)); DOT2X4(u5, H2C(hB.y));
                DOT2X4(u6, H2C(hB.z)); DOT2X4(u7, H2C(hB.w));
            }
            {
                uint4 u0=wrow[8*8+q],  u1=wrow[9*8+q],  u2=wrow[10*8+q], u3=wrow[11*8+q];
                uint4 u4=wrow[12*8+q], u5=wrow[13*8+q], u6=wrow[14*8+q], u7=wrow[15*8+q];
                DOT2X4(u0, H2C(hC.x)); DOT2X4(u1, H2C(hC.y));
                DOT2X4(u2, H2C(hC.z)); DOT2X4(u3, H2C(hC.w));
                DOT2X4(u4, H2C(hD.x)); DOT2X4(u5, H2C(hD.y));
                DOT2X4(u6, H2C(hD.z)); DOT2X4(u7, H2C(hD.w));
            }
            #pragma unroll
            for (int m=1; m<8; m<<=1){
                a0 += __shfl_xor(a0,m); a1 += __shfl_xor(a1,m);
                a2 += __shfl_xor(a2,m); a3 += __shfl_xor(a3,m);
            }
            if (q==0) gpart4[g4] = make_float4(a0,a1,a2,a3);
        }
        if (t < 272){
            const int cg = t>>3, qq = t&7;
            const uint4* wrow = wpg + (hf*34+cg)*128;
            uint4 hA = hb2q[qq*4+0], hB = hb2q[qq*4+1], hC = hb2q[qq*4+2], hD = hb2q[qq*4+3];
            float pa0=0.f, pa1=0.f, pa2=0.f, pa3=0.f;
            {
                uint4 u0=wrow[0*8+qq], u1=wrow[1*8+qq], u2=wrow[2*8+qq], u3=wrow[3*8+qq];
                uint4 u4=wrow[4*8+qq], u5=wrow[5*8+qq], u6=wrow[6*8+qq], u7=wrow[7*8+qq];
                DOT2P(u0, H2C(hA.x)); DOT2P(u1, H2C(hA.y));
                DOT2P(u2, H2C(hA.z)); DOT2P(u3, H2C(hA.w));
                DOT2P(u4, H2C(hB.x)); DOT2P(u5, H2C(hB.y));
                DOT2P(u6, H2C(hB.z)); DOT2P(u7, H2C(hB.w));
            }
            {
                uint4 u0=wrow[8*8+qq],  u1=wrow[9*8+qq],  u2=wrow[10*8+qq], u3=wrow[11*8+qq];
                uint4 u4=wrow[12*8+qq], u5=wrow[13*8+qq], u6=wrow[14*8+qq], u7=wrow[15*8+qq];
                DOT2P(u0, H2C(hC.x)); DOT2P(u1, H2C(hC.y));
                DOT2P(u2, H2C(hC.z)); DOT2P(u3, H2C(hC.w));
                DOT2P(u4, H2C(hD.x)); DOT2P(u5, H2C(hD.y));
                DOT2P(u6, H2C(hD.z)); DOT2P(u7, H2C(hD.w));
            }
            #pragma unroll
            for (int m=1; m<8; m<<=1){
                pa0 += __shfl_xor(pa0,m); pa1 += __shfl_xor(pa1,m);
                pa2 += __shfl_xor(pa2,m); pa3 += __shfl_xor(pa3,m);
            }
            if (qq==0){
                #pragma unroll
                for (int j=0; j<4; ++j){
                    float aj = (j==0)?pa0:((j==1)?pa1:((j==2)?pa2:pa3));
                    int cl = cg*4+j;
                    if (cl < 134){
                        int rc = hf*134+cl;
                        float pv = clipf(aj + bpp[rc]);
                        float dv = decodeP(rc, pv);
                        pOwn[cl] = dv;
                        if (rc < 64) kv[0][rc] = dv;
                        else if (rc < 70) prmS[rc-64] = dv;
                        else if (rc < 134) kv[1][rc-70] = dv;
                        else if (rc < 140) prmS[6+rc-134] = dv;
                        else if (rc < 204) ebuf[rc-140] = dv;
                        else abuf[rc-204] = dv;
                    }
                }
            }
        } else if (t < 528){
            const int idx = t-272, n = idx>>1, m0 = (idx&1)*32;
            float s = 0.f;
            #pragma unroll 8
            for (int m=m0; m<m0+32; ++m){ float v=Mem[n][m]; s=fmaf(v,v,s); }
            s += __shfl_xor(s,1);
            if (!(idx&1)) Mn[n] = sqrtf(s);
        } else if (t < 656){
            const int o = (t-528)>>4, l16 = (t-528)&15;
            float s = 0.f;
            #pragma unroll
            for (int j=0; j<16; ++j){
                const int i = l16 + (j<<4);
                s = fmaf(hbuf[i], W_o[i*OUT_ + o], s);
            }
            s += __shfl_xor(s,1); s += __shfl_xor(s,2);
            s += __shfl_xor(s,4); s += __shfl_xor(s,8);
            if (l16==0) jpart[o] = s;
        } else if (t >= 656 && t < 661){
            if (step+1 < T_){
                const int p = t-656;
                const int e0 = 2*p, e1 = e0+1;
                const float* xin = inputs + (b*T_ + step+1)*IN_DIM_;
                h2_t v;
                v.x = (_Float16)((e0<IN_DIM_) ? xin[e0] : 0.f);
                v.y = (_Float16)((e1<IN_DIM_) ? xin[e1] : 0.f);
                xr2[32+p] = v;
            }
        }
        __syncthreads();                          // drains volatile p stores
        if (t==0){
            flg[2+hf] = step+1;
            while (flg[2+(hf^1)] < step+1) __builtin_amdgcn_s_sleep(8);
        }
        __syncthreads();
        if (t < 134){                              // route partner's decoded params
            float dv = pOth[t];
            int rc = (hf^1)*134 + t;
            if (rc < 64) kv[0][rc] = dv;
            else if (rc < 70) prmS[rc-64] = dv;
            else if (rc < 134) kv[1][rc-70] = dv;
            else if (rc < 140) prmS[6+rc-134] = dv;
            else if (rc < 204) ebuf[rc-140] = dv;
            else abuf[rc-204] = dv;
        }
        __syncthreads();

        // ---- F: inner products + scal decode ----
        {
            const int h = t>>9, n = (t>>2)&127, qm = t&3, m0 = qm*16;
            float s = 0.f;
            #pragma unroll 8
            for (int m=m0; m<m0+16; ++m) s = fmaf(kv[h][m], Mem[n][m], s);
            s += __shfl_xor(s,1); s += __shfl_xor(s,2);
            if (qm==0) innr[h][n] = s;
        }
        if (t < 2){
            const int h = t;
            const float* ps = prmS + 6*h;
            scal[h]   = splus(ps[0]);
            scal[2+h] = sigf(ps[1]);
            float p0=ps[2], p1=ps[3], p2=ps[4];
            float mx = fmaxf(p0, fmaxf(p1, p2));
            float e0=__expf(p0-mx), e1=__expf(p1-mx), e2=__expf(p2-mx);
            float s = e0+e1+e2;
            scal[6+3*h]=e0/s; scal[7+3*h]=e1/s; scal[8+3*h]=e2/s;
            scal[4+h] = 1.f + splus(ps[5]);
        }
        __syncthreads();

        // ---- G: key norm + content softmax + interp + shift + sharpen ----
        if (t < 128){
            const int h = t>>6, l = ln;
            float kvl = kv[h][l];
            float kn2 = kvl*kvl;
            for (int off=32; off>=1; off>>=1) kn2 += __shfl_xor(kn2, off);
            float kn = sqrtf(kn2);
            float beta = scal[h], g = scal[2+h];
            float bk0 = beta * innr[h][l]   /(kn*Mn[l]   +1e-8f);
            float bk1 = beta * innr[h][l+64]/(kn*Mn[l+64]+1e-8f);
            float mx = fmaxf(bk0,bk1);
            for (int off=32; off>=1; off>>=1) mx = fmaxf(mx, __shfl_xor(mx, off));
            float e0=__expf(bk0-mx), e1=__expf(bk1-mx);
            float s=e0+e1;
            for (int off=32; off>=1; off>>=1) s += __shfl_xor(s, off);
            float wc0=e0/s, wc1=e1/s;
            wgs[h][l]    = g*wc0 + (1.f-g)*wtab[h][l];
            wgs[h][l+64] = g*wc1 + (1.f-g)*wtab[h][l+64];
            float gamma = scal[4+h];
            float s0=scal[6+3*h], s1=scal[7+3*h], s2=scal[8+3*h];
            const int n0=l, n1=l+64;
            float wt0 = s0*wgs[h][(n0+1)&127] + s1*wgs[h][n0] + s2*wgs[h][(n0+127)&127];
            float wt1 = s0*wgs[h][(n1+1)&127] + s1*wgs[h][n1] + s2*wgs[h][(n1+127)&127];
            float wp0 = __powf(wt0, gamma), wp1 = __powf(wt1, gamma);
            float ss = wp0+wp1;
            for (int off=32; off>=1; off>>=1) ss += __shfl_xor(ss, off);
            float inv = 1.0f/(ss+1e-8f);
            wtab[h][n0] = wp0*inv; wtab[h][n1] = wp1*inv;
        }
        __syncthreads();

        // ---- H: memory write + fused read-head partials ----
        {
            const float el = ebuf[ln], al = abuf[ln];
            const int n0 = wv*8;
            float racc = 0.f;
            #pragma unroll
            for (int k=0; k<8; ++k){
                const int n = n0+k;
                float ww = wtab[1][n];
                float wr = wtab[0][n];
                float v = Mem[n][ln]*(1.0f - ww*el) + ww*al;
                Mem[n][ln] = v;
                racc = fmaf(wr, v, racc);
            }
            rpart[wv][ln] = racc;
        }
        __syncthreads();

        // ---- J: r finalize + output (hf==0 writes) + xr2 r-pack ----
        if (t < 512){
            const int o = wv;
            float rm = 0.f;
            #pragma unroll
            for (int k=0; k<16; ++k) rm += rpart[k][ln];
            float s = rm * W_o[(U_+ln)*OUT_ + o];
            for (int off=32; off>=1; off>>=1) s += __shfl_xor(s, off);
            if (ln==0 && hf==0 && step>=TSTART){
                float logit = clipf(s + jpart[o] + b_o[o]);
                out[((b*(T_-TSTART)) + (step-TSTART))*OUT_ + o] = sigf(logit);
            }
        } else if (t < 576){
            float rm = 0.f;
            #pragma unroll
            for (int k=0; k<16; ++k) rm += rpart[k][ln];
            float other = __shfl_xor(rm, 1);
            if (!(ln&1)){
                h2_t v; v.x = (_Float16)rm; v.y = (_Float16)other;
                xr2[ln>>1] = v;
            }
        }
        __syncthreads();
    }
}

extern "C" void kernel_launch(void* const* d_in, const int* in_sizes, int n_in,
                              void* d_out, int out_size, void* d_ws, size_t ws_size,
                              hipStream_t stream) {
    const float* inputs = (const float*)d_in[0];
    const float* W_x    = (const float*)d_in[1];
    const float* W_h    = (const float*)d_in[2];
    const float* b_lstm = (const float*)d_in[3];
    const float* W_p    = (const float*)d_in[4];
    const float* b_p    = (const float*)d_in[5];
    const float* W_o    = (const float*)d_in[6];
    const float* b_o    = (const float*)d_in[7];
    const float* r0     = (const float*)d_in[8];
    const float* w0     = (const float*)d_in[9];
    float* out = (float*)d_out;

    char* ws = (char*)d_ws;
    uint4*  wx2 = (uint4*)(ws + WX2_OFF);
    uint4*  wh2 = (uint4*)(ws + WHG_OFF);
    uint4*  wp2 = (uint4*)(ws + WPG_OFF);
    float4* blh = (float4*)(ws + BLH_OFF);
    float*  bpp = (float*)(ws + BPP_OFF);
    char*   comm = ws + COMM_OFF;

    hipMemsetAsync(comm, 0, COMM_SZ, stream);
    prep_kernel<<<512, 256, 0, stream>>>(W_x, W_h, W_p, b_lstm, b_p, wx2, wh2, wp2, blh, bpp);
    ntm_kernel<<<2*B_, 1024, 0, stream>>>(inputs, W_o, b_o, r0, w0,
                                          wx2, wh2, wp2, blh, bpp, comm, out);
}